// Round 1
// baseline (119.043 us; speedup 1.0000x reference)
//
#include <hip/hip_runtime.h>

#define BETA_F 0.9f

__device__ __forceinline__ float fsigmoid(float x) {
    // sigmoid(x) = 1 / (1 + exp(-x)); fast rcp + hw exp, plenty for 0.165 absmax
    float e = __expf(-x);
    return __builtin_amdgcn_rcpf(1.0f + e);
}

// One block per (b,i): grid 256, block 256 threads.
// Computes one full WalkLayer iteration: out = mat*pin + (1-mat)*sum_k sigmoid((pin@W)[b,i,k,:] * pin[b,k,j,:])
__global__ __launch_bounds__(256) void walk_iter_kernel(
    const float* __restrict__ pin,   // [8192][128]
    const float* __restrict__ W,     // [128][128]
    float* __restrict__ pout)        // [8192][128]
{
    constexpr int IT = 32, EE = 128;
    __shared__ float A[IT][132];     // pairs rows (b,i,0..31); +4 pad kills bank conflicts
    __shared__ float G[IT][EE];      // bilin rows (b,i,0..31)

    const int blk = blockIdx.x;      // b*32 + i
    const int i   = blk & 31;
    const int b   = blk >> 5;
    const int t   = threadIdx.x;
    const int base = blk * (IT * EE);

    // ---- stage A (32 rows x 128 floats, coalesced float4) ----
    {
        const float4* src = (const float4*)(pin + base);
        #pragma unroll
        for (int q = 0; q < 4; ++q) {
            int f = t + 256 * q;               // float4 index 0..1023
            float4 v = src[f];
            int row = f >> 5;                  // 32 float4 per row
            int col = (f & 31) << 2;
            A[row][col]   = v.x; A[row][col+1] = v.y;
            A[row][col+2] = v.z; A[row][col+3] = v.w;
        }
    }
    __syncthreads();

    // ---- GEMM phase: G = A @ W  (thread tile: 4 k-rows x 4 e-cols) ----
    {
        const int kg = t >> 5;                 // 0..7 -> k rows kg*4..kg*4+3
        const int eg = t & 31;                 // e chunk eg*4..eg*4+3
        const int k0 = kg * 4;
        float acc[4][4] = {};
        for (int d = 0; d < EE; d += 4) {
            float4 a0 = *(const float4*)&A[k0+0][d];
            float4 a1 = *(const float4*)&A[k0+1][d];
            float4 a2 = *(const float4*)&A[k0+2][d];
            float4 a3 = *(const float4*)&A[k0+3][d];
            float ar[4][4] = {
                {a0.x, a0.y, a0.z, a0.w},
                {a1.x, a1.y, a1.z, a1.w},
                {a2.x, a2.y, a2.z, a2.w},
                {a3.x, a3.y, a3.z, a3.w},
            };
            #pragma unroll
            for (int dd = 0; dd < 4; ++dd) {
                float4 w = *(const float4*)(W + (d + dd) * EE + eg * 4);
                #pragma unroll
                for (int r = 0; r < 4; ++r) {
                    acc[r][0] += ar[r][dd] * w.x;
                    acc[r][1] += ar[r][dd] * w.y;
                    acc[r][2] += ar[r][dd] * w.z;
                    acc[r][3] += ar[r][dd] * w.w;
                }
            }
        }
        #pragma unroll
        for (int r = 0; r < 4; ++r) {
            float4 v = make_float4(acc[r][0], acc[r][1], acc[r][2], acc[r][3]);
            *(float4*)&G[k0 + r][eg * 4] = v;
        }
    }
    __syncthreads();

    // ---- walk phase ----
    // thread -> j = t>>3, 8 lanes per j; each lane owns e = g*4 + 32*q (q=0..3)
    const int j = t >> 3;
    const int g = t & 7;
    const bool selfrow = (i == j);
    const unsigned grpShift = (unsigned)(t & 63) & 56u;  // 8-lane group base within wave

    float4 sacc[4] = {};
    int cnt = 0;

    if (!selfrow) {
        for (int k = 0; k < IT; ++k) {
            if (k == i || k == j) continue;    // eq_mask -> -inf -> sigmoid 0
            const float* prow = pin + (size_t)((b * IT + k) * IT + j) * EE;
            float4 m[4];
            #pragma unroll
            for (int q = 0; q < 4; ++q) {
                int e = g * 4 + 32 * q;
                float4 p  = *(const float4*)(prow + e);
                float4 gg = *(const float4*)&G[k][e];
                m[q].x = gg.x * p.x; m[q].y = gg.y * p.y;
                m[q].z = gg.z * p.z; m[q].w = gg.w * p.w;
            }
            // zero_mask: if product == 0 for ALL 128 e of this (j,k), row becomes -inf
            bool nz = false;
            #pragma unroll
            for (int q = 0; q < 4; ++q)
                nz = nz || (m[q].x != 0.0f) || (m[q].y != 0.0f) ||
                           (m[q].z != 0.0f) || (m[q].w != 0.0f);
            unsigned long long bal = __ballot(nz);
            bool groupnz = ((bal >> grpShift) & 0xFFull) != 0ull;
            if (!groupnz) continue;
            ++cnt;
            #pragma unroll
            for (int q = 0; q < 4; ++q) {
                sacc[q].x += fsigmoid(m[q].x);
                sacc[q].y += fsigmoid(m[q].y);
                sacc[q].z += fsigmoid(m[q].z);
                sacc[q].w += fsigmoid(m[q].w);
            }
        }
    }

    // ---- epilogue: out = mat*pairs + (1-mat)*new ----
    const float matv = (cnt == 0) ? 1.0f : BETA_F;
    const float om   = 1.0f - matv;
    float* orow = pout + (size_t)(blk * IT + j) * EE;
    #pragma unroll
    for (int q = 0; q < 4; ++q) {
        int e = g * 4 + 32 * q;
        float4 pr = *(const float4*)&A[j][e];
        float4 o;
        o.x = matv * pr.x + om * sacc[q].x;
        o.y = matv * pr.y + om * sacc[q].y;
        o.z = matv * pr.z + om * sacc[q].z;
        o.w = matv * pr.w + om * sacc[q].w;
        *(float4*)(orow + e) = o;
    }
}

extern "C" void kernel_launch(void* const* d_in, const int* in_sizes, int n_in,
                              void* d_out, int out_size, void* d_ws, size_t ws_size,
                              hipStream_t stream) {
    (void)in_sizes; (void)n_in; (void)out_size; (void)ws_size;
    const float* pairs = (const float*)d_in[0];
    const float* W     = (const float*)d_in[1];
    float* tmp = (float*)d_ws;    // iter-1 output (4 MB)
    float* out = (float*)d_out;

    // ITER = 2, ping-pong through workspace; kernel boundary = device-wide sync
    walk_iter_kernel<<<256, 256, 0, stream>>>(pairs, W, tmp);
    walk_iter_kernel<<<256, 256, 0, stream>>>(tmp,   W, out);
}